// Round 12
// baseline (189.284 us; speedup 1.0000x reference)
//
#include <hip/hip_runtime.h>
#include <hip/hip_bf16.h>
#include <math.h>

#define D_MODEL 1024
#define SEQ     2048
#define BATCH   2
#define NHEAD   16
#define DKH     64
#define BH      (BATCH * NHEAD)   // 32

typedef unsigned short u16;
typedef unsigned int   u32;
typedef __bf16 bf16x8 __attribute__((ext_vector_type(8)));
typedef float  f32x4  __attribute__((ext_vector_type(4)));

#define MFMA16(a, b, c) __builtin_amdgcn_mfma_f32_16x16x32_bf16((a), (b), (c), 0, 0, 0)
#define AS1 __attribute__((address_space(1)))
#define AS3 __attribute__((address_space(3)))

// 1/(8*ln2): folded into Q so softmax is exp2(s) with no fma and no shift
#define QSCALE 0.18033688f

__device__ __forceinline__ u16 f2bf(float x) {
    u32 u = __float_as_uint(x);
    u += 0x7fffu + ((u >> 16) & 1u);   // RNE (finite data)
    return (u16)(u >> 16);
}
__device__ __forceinline__ float bf2f(u16 b) {
    return __uint_as_float(((u32)b) << 16);
}
// async global->LDS, 16B/lane; lds dest wave-uniform (lane*16 implicit)
__device__ __forceinline__ void gl16(const u16* g, void* lds) {
    __builtin_amdgcn_global_load_lds((const AS1 u32*)g, (AS3 u32*)lds, 16, 0, 0);
}

// ---------------------------------------------------------------------------
// Conversions, one launch:
//   blocks [0, 4096)    : x fp32 -> bf16 (hi only)
//   blocks [4096, 5120) : W [K][N] fp32 -> WT bf16 [N][K]; hi for all 4,
//                         lo ONLY for Wo (bz==3).
// ---------------------------------------------------------------------------
__global__ __launch_bounds__(256) void conv_all(
    const float* __restrict__ x, u16* __restrict__ Xh, int n4,
    const float* __restrict__ W0, const float* __restrict__ W1,
    const float* __restrict__ W2, const float* __restrict__ W3,
    u16* __restrict__ H0, u16* __restrict__ L0, u16* __restrict__ H1, u16* __restrict__ L1,
    u16* __restrict__ H2, u16* __restrict__ L2, u16* __restrict__ H3, u16* __restrict__ L3)
{
    const int t = threadIdx.x;
    if ((int)blockIdx.x < 4096) {
        int i = blockIdx.x * 256 + t;
        if (i >= n4) return;
        float4 v = reinterpret_cast<const float4*>(x)[i];
        uint2 H;
        H.x = f2bf(v.x) | ((u32)f2bf(v.y) << 16);
        H.y = f2bf(v.z) | ((u32)f2bf(v.w) << 16);
        reinterpret_cast<uint2*>(Xh)[i] = H;
        return;
    }
    int id = blockIdx.x - 4096;          // 0..1023
    int bx = id & 15, by = (id >> 4) & 15, bz = id >> 8;
    const float* W; u16 *Ht, *Lt;
    if (bz == 0)      { W = W0; Ht = H0; Lt = L0; }
    else if (bz == 1) { W = W1; Ht = H1; Lt = L1; }
    else if (bz == 2) { W = W2; Ht = H2; Lt = L2; }
    else              { W = W3; Ht = H3; Lt = L3; }

    __shared__ float T[64][65];
    const int n0 = bx * 64, k0 = by * 64;
    #pragma unroll
    for (int i = 0; i < 4; ++i) {
        int f = t + i * 256;
        int kr = f >> 4, ns = (f & 15) * 4;
        float4 v = *reinterpret_cast<const float4*>(&W[(size_t)(k0 + kr) * D_MODEL + n0 + ns]);
        T[kr][ns + 0] = v.x; T[kr][ns + 1] = v.y; T[kr][ns + 2] = v.z; T[kr][ns + 3] = v.w;
    }
    __syncthreads();
    #pragma unroll
    for (int i = 0; i < 4; ++i) {
        int f = t + i * 256;
        int nr = f >> 4, ks = (f & 15) * 4;
        u16 hh[4], ll[4];
        #pragma unroll
        for (int j = 0; j < 4; ++j) {
            float xv = T[ks + j][nr];
            u16 hb = f2bf(xv);
            hh[j] = hb;
            ll[j] = f2bf(xv - bf2f(hb));
        }
        uint2 H, L;
        H.x = hh[0] | ((u32)hh[1] << 16); H.y = hh[2] | ((u32)hh[3] << 16);
        L.x = ll[0] | ((u32)ll[1] << 16); L.y = ll[2] | ((u32)ll[3] << 16);
        size_t o = (size_t)(n0 + nr) * D_MODEL + k0 + ks;
        *reinterpret_cast<uint2*>(&Ht[o]) = H;
        if (bz == 3)
            *reinterpret_cast<uint2*>(&Lt[o]) = L;
    }
}

// ---------------------------------------------------------------------------
// Fused QKV GEMM, SINGLE-term: C = Ah @ Bh^T + bias (verified absmax
// 1.46e-3 vs 3.9e-3 threshold). 128x64 tile, 256 threads (4 waves, wave
// tile 64x32); LDS 40KB total.
// R12: SINGLE-phase, 2-tile-deep counted-vmcnt pipeline. Per iter:
//   vmcnt(5) [own 5 chunks of tile it done; tiles it,it+1 in flight]
//   -> barrier -> 10 ds_reads -> lgkmcnt(0)+sched_barrier (rule #18)
//   -> barrier (WAR: all waves done reading buf) -> issue tile it+2 into
//   the freed buffer -> 24 MFMAs. Peeled last iter waits vmcnt(0).
// ---------------------------------------------------------------------------
__global__ __launch_bounds__(256, 2) void gemm_qkv(
    const u16* __restrict__ AhG,
    const u16* __restrict__ Bqh, const u16* __restrict__ Bkh, const u16* __restrict__ Bvh,
    const float* __restrict__ bq, const float* __restrict__ bk, const float* __restrict__ bv,
    u16* __restrict__ Qb, u16* __restrict__ Kb, u16* __restrict__ Vb)
{
    constexpr int K = D_MODEL, N = D_MODEL;
    __shared__ u16 LB[2][10240];   // per buf 20KB: A(8KB) | Bqh(4KB) | Bkh(4KB) | Bvh(4KB)

    const int tid  = threadIdx.x;
    const int wv   = tid >> 6;          // 0..3
    const int lane = tid & 63;
    const int quad = lane >> 4;
    const int l16  = lane & 15;
    const int wm   = wv & 1, wn = wv >> 1;   // wave tile 64 rows x 32 cols
    const int brow = blockIdx.y * 128, bcol = blockIdx.x * 64;

    // 5 staging chunks per wave: A(8 chunks across waves) + Bqh/Bkh/Bvh (4 each)
    const u16* ptrs[4] = { AhG, Bqh, Bkh, Bvh };
    const int abase[4] = { 0, 8192, 12288, 16384 };   // byte offs, sum = 20KB
    const u16* sp[5];
    int sldb[5];
    #pragma unroll
    for (int j = 0; j < 5; ++j) {
        int a, cc;
        if (j < 3)      { int c = wv * 3 + j; if (c < 8) { a = 0; cc = c; } else { a = 1; cc = c - 8; } }
        else if (j == 3){ a = 2; cc = wv; }
        else            { a = 3; cc = wv; }
        int row  = cc * 16 + (lane >> 2);
        int gseg = (lane & 3) ^ ((lane >> 3) & 3);
        int rbase = (a == 0) ? brow : bcol;
        sp[j]   = ptrs[a] + (size_t)(rbase + row) * K + gseg * 8;
        sldb[j] = abase[a] + cc * 1024;
    }

    int aro[4], bro[2];
    #pragma unroll
    for (int i = 0; i < 4; ++i) {
        int mr = wm * 64 + i * 16 + l16;
        aro[i] = mr * 64 + ((quad ^ ((mr >> 1) & 3)) * 16);
    }
    #pragma unroll
    for (int i = 0; i < 2; ++i) {
        int nr = wn * 32 + i * 16 + l16;
        bro[i] = nr * 64 + ((quad ^ ((nr >> 1) & 3)) * 16);
    }

    f32x4 acc[3][4][2] = {};

    auto mm = [&](int m, bf16x8 (&ah)[4], bf16x8 b0, bf16x8 b1) {
        #pragma unroll
        for (int mi = 0; mi < 4; ++mi) {
            f32x4 c0 = acc[m][mi][0], c1 = acc[m][mi][1];
            c0 = MFMA16(ah[mi], b0, c0);
            c1 = MFMA16(ah[mi], b1, c1);
            acc[m][mi][0] = c0; acc[m][mi][1] = c1;
        }
    };

    // prologue: 2 tiles in flight (issue order = iter order; vmcnt relies on it)
    #pragma unroll
    for (int j = 0; j < 5; ++j)
        gl16(sp[j], (char*)LB[0] + sldb[j]);
    #pragma unroll
    for (int j = 0; j < 5; ++j)
        gl16(sp[j] + 32, (char*)LB[1] + sldb[j]);

    for (int it = 0; it < K / 32 - 1; ++it) {
        const int cur = it & 1;

        // own 5 chunks of tile it complete (5 newer = tile it+1 still in flight)
        asm volatile("s_waitcnt vmcnt(5)" ::: "memory");
        __builtin_amdgcn_s_barrier();

        bf16x8 ah[4], q0, q1, k0, k1, v0, v1;
        #pragma unroll
        for (int i = 0; i < 4; ++i)
            ah[i] = *reinterpret_cast<const bf16x8*>((const char*)LB[cur] + aro[i]);
        q0 = *reinterpret_cast<const bf16x8*>((const char*)LB[cur] + 8192 + bro[0]);
        q1 = *reinterpret_cast<const bf16x8*>((const char*)LB[cur] + 8192 + bro[1]);
        k0 = *reinterpret_cast<const bf16x8*>((const char*)LB[cur] + 12288 + bro[0]);
        k1 = *reinterpret_cast<const bf16x8*>((const char*)LB[cur] + 12288 + bro[1]);
        v0 = *reinterpret_cast<const bf16x8*>((const char*)LB[cur] + 16384 + bro[0]);
        v1 = *reinterpret_cast<const bf16x8*>((const char*)LB[cur] + 16384 + bro[1]);

        // drain own ds_reads, then barrier: after it, every wave is done
        // reading LB[cur] -> safe to overwrite with tile it+2
        asm volatile("s_waitcnt lgkmcnt(0)" ::: "memory");
        __builtin_amdgcn_sched_barrier(0);
        __builtin_amdgcn_s_barrier();

        if (it + 2 < K / 32) {
            const int k2 = (it + 2) * 32;
            #pragma unroll
            for (int j = 0; j < 5; ++j)
                gl16(sp[j] + k2, (char*)LB[cur] + sldb[j]);
        }

        __builtin_amdgcn_s_setprio(1);
        mm(0, ah, q0, q1);
        mm(1, ah, k0, k1);
        mm(2, ah, v0, v1);
        __builtin_amdgcn_s_setprio(0);
    }

    // ---- last iteration peeled: only its own 5 outstanding -> vmcnt(0) ----
    {
        const int cur = (K / 32 - 1) & 1;
        asm volatile("s_waitcnt vmcnt(0)" ::: "memory");
        __builtin_amdgcn_s_barrier();
        bf16x8 ah[4], q0, q1, k0, k1, v0, v1;
        #pragma unroll
        for (int i = 0; i < 4; ++i)
            ah[i] = *reinterpret_cast<const bf16x8*>((const char*)LB[cur] + aro[i]);
        q0 = *reinterpret_cast<const bf16x8*>((const char*)LB[cur] + 8192 + bro[0]);
        q1 = *reinterpret_cast<const bf16x8*>((const char*)LB[cur] + 8192 + bro[1]);
        k0 = *reinterpret_cast<const bf16x8*>((const char*)LB[cur] + 12288 + bro[0]);
        k1 = *reinterpret_cast<const bf16x8*>((const char*)LB[cur] + 12288 + bro[1]);
        v0 = *reinterpret_cast<const bf16x8*>((const char*)LB[cur] + 16384 + bro[0]);
        v1 = *reinterpret_cast<const bf16x8*>((const char*)LB[cur] + 16384 + bro[1]);
        __builtin_amdgcn_s_setprio(1);
        mm(0, ah, q0, q1);
        mm(1, ah, k0, k1);
        mm(2, ah, v0, v1);
        __builtin_amdgcn_s_setprio(0);
    }

    // epilogue: Q pre-scaled for exp2-softmax; all flat bf16
    #pragma unroll
    for (int m = 0; m < 3; ++m) {
        const float* bias = (m == 0) ? bq : (m == 1) ? bk : bv;
        u16* out = (m == 0) ? Qb : (m == 1) ? Kb : Vb;
        const float sc = (m == 0) ? QSCALE : 1.0f;
        #pragma unroll
        for (int mi = 0; mi < 4; ++mi) {
            #pragma unroll
            for (int ni = 0; ni < 2; ++ni) {
                int col = bcol + wn * 32 + ni * 16 + l16;
                float bvv = bias[col];
                #pragma unroll
                for (int r = 0; r < 4; ++r) {
                    int row = brow + wm * 64 + mi * 16 + quad * 4 + r;
                    out[(size_t)row * N + col] = f2bf((acc[m][mi][ni][r] + bvv) * sc);
                }
            }
        }
    }
}

// ---------------------------------------------------------------------------
// Out-proj GEMM, 2-term: out = Ctx @ (Woh+Wol)^T + bo, fp32 out.
// 128x64 tile, 256 threads (4 waves), LDS 32KB total.
// 2-phase counted-vmcnt: ph0: 3 = A+Bh, ph1: 1 = Bl; waits 1/3; peel 1/0.
// ---------------------------------------------------------------------------
__global__ __launch_bounds__(256, 2) void gemm_oproj(
    const u16* __restrict__ AhG, const u16* __restrict__ Bh, const u16* __restrict__ Bl,
    const float* __restrict__ bias, float* __restrict__ Cf)
{
    constexpr int K = D_MODEL, N = D_MODEL;
    __shared__ u16 LB[2][8192];   // per buf 16KB: A(8KB) | Bh(4KB) | Bl(4KB)

    const int tid  = threadIdx.x;
    const int wv   = tid >> 6;          // 0..3
    const int lane = tid & 63;
    const int quad = lane >> 4;
    const int l16  = lane & 15;
    const int wm   = wv & 1, wn = wv >> 1;   // wave tile 64 rows x 32 cols
    const int brow = blockIdx.y * 128, bcol = blockIdx.x * 64;

    // 4 staging chunks per wave: j=0..2 phase0 (A 8 + Bh 4), j=3 phase1 (Bl)
    const u16* ptrs[3] = { AhG, Bh, Bl };
    const int abase[3] = { 0, 8192, 12288 };   // byte offs within 16KB buffer
    const u16* sp[4];
    int sldb[4];
    #pragma unroll
    for (int j = 0; j < 4; ++j) {
        int a, cc;
        if (j < 3) { int c = wv * 3 + j;  a = (c < 8) ? 0 : 1; cc = (c < 8) ? c : (c - 8); }
        else       { a = 2; cc = wv; }
        int row  = cc * 16 + (lane >> 2);
        int gseg = (lane & 3) ^ ((lane >> 3) & 3);
        int rbase = (a == 0) ? brow : bcol;
        sp[j]   = ptrs[a] + (size_t)(rbase + row) * K + gseg * 8;
        sldb[j] = abase[a] + cc * 1024;
    }

    int aro[4], bro[2];
    #pragma unroll
    for (int i = 0; i < 4; ++i) {
        int mr = wm * 64 + i * 16 + l16;
        aro[i] = mr * 64 + ((quad ^ ((mr >> 1) & 3)) * 16);
    }
    #pragma unroll
    for (int i = 0; i < 2; ++i) {
        int nr = wn * 32 + i * 16 + l16;
        bro[i] = nr * 64 + ((quad ^ ((nr >> 1) & 3)) * 16);
    }

    f32x4 acc[4][2] = {};

    auto mmc = [&](bf16x8 (&ah)[4], bf16x8 b0, bf16x8 b1) {
        __builtin_amdgcn_s_setprio(1);
        #pragma unroll
        for (int mi = 0; mi < 4; ++mi) {
            f32x4 c0 = acc[mi][0], c1 = acc[mi][1];
            c0 = MFMA16(ah[mi], b0, c0);
            c1 = MFMA16(ah[mi], b1, c1);
            acc[mi][0] = c0; acc[mi][1] = c1;
        }
        __builtin_amdgcn_s_setprio(0);
    };

    // prologue: issue iter-0 loads in phase order
    #pragma unroll
    for (int j = 0; j < 4; ++j)
        gl16(sp[j], (char*)LB[0] + sldb[j]);

    for (int it = 0; it < K / 32 - 1; ++it) {
        const int cur = it & 1, nx = cur ^ 1;
        const int k1 = (it + 1) * 32;
        bf16x8 ah[4], b0, b1;

        // ---- phase 0 : hi ---- (oldest 3 = this iter's A,Bh chunks)
        asm volatile("s_waitcnt vmcnt(1)" ::: "memory");
        __builtin_amdgcn_s_barrier();
        #pragma unroll
        for (int i = 0; i < 4; ++i)
            ah[i] = *reinterpret_cast<const bf16x8*>((const char*)LB[cur] + aro[i]);
        b0 = *reinterpret_cast<const bf16x8*>((const char*)LB[cur] + 8192 + bro[0]);
        b1 = *reinterpret_cast<const bf16x8*>((const char*)LB[cur] + 8192 + bro[1]);
        gl16(sp[0] + k1, (char*)LB[nx] + sldb[0]);
        gl16(sp[1] + k1, (char*)LB[nx] + sldb[1]);
        gl16(sp[2] + k1, (char*)LB[nx] + sldb[2]);
        mmc(ah, b0, b1);

        // ---- phase 1 : lo ---- (oldest 1 = this iter's Bl chunk)
        asm volatile("s_waitcnt vmcnt(3)" ::: "memory");
        __builtin_amdgcn_s_barrier();
        b0 = *reinterpret_cast<const bf16x8*>((const char*)LB[cur] + 12288 + bro[0]);
        b1 = *reinterpret_cast<const bf16x8*>((const char*)LB[cur] + 12288 + bro[1]);
        gl16(sp[3] + k1, (char*)LB[nx] + sldb[3]);
        mmc(ah, b0, b1);
    }

    // ---- last iteration peeled: no prefetch; exact drain counts ----
    {
        const int cur = (K / 32 - 1) & 1;
        bf16x8 ah[4], b0, b1;

        asm volatile("s_waitcnt vmcnt(1)" ::: "memory");
        __builtin_amdgcn_s_barrier();
        #pragma unroll
        for (int i = 0; i < 4; ++i)
            ah[i] = *reinterpret_cast<const bf16x8*>((const char*)LB[cur] + aro[i]);
        b0 = *reinterpret_cast<const bf16x8*>((const char*)LB[cur] + 8192 + bro[0]);
        b1 = *reinterpret_cast<const bf16x8*>((const char*)LB[cur] + 8192 + bro[1]);
        mmc(ah, b0, b1);

        asm volatile("s_waitcnt vmcnt(0)" ::: "memory");
        __builtin_amdgcn_s_barrier();
        b0 = *reinterpret_cast<const bf16x8*>((const char*)LB[cur] + 12288 + bro[0]);
        b1 = *reinterpret_cast<const bf16x8*>((const char*)LB[cur] + 12288 + bro[1]);
        mmc(ah, b0, b1);
    }

    #pragma unroll
    for (int mi = 0; mi < 4; ++mi) {
        #pragma unroll
        for (int ni = 0; ni < 2; ++ni) {
            int col = bcol + wn * 32 + ni * 16 + l16;
            float bvv = bias[col];
            #pragma unroll
            for (int r = 0; r < 4; ++r) {
                int row = brow + wm * 64 + mi * 16 + quad * 4 + r;
                Cf[(size_t)row * N + col] = acc[mi][ni][r] + bvv;
            }
        }
    }
}

// ---------------------------------------------------------------------------
// V bf16 flat [BH][SEQ][64] -> Vt bf16 [BH][64][SEQ], with k PERMUTED within
// each 64-tile: p(k=16*t4+l) = 4*l + t4. Matches attn's packed-b64 P layout.
// ---------------------------------------------------------------------------
__global__ __launch_bounds__(256) void v_transpose(
    const u16* __restrict__ V, u16* __restrict__ Vt)
{
    __shared__ u16 T[64][72];
    const int bh = blockIdx.y, st = blockIdx.x;
    const u16* src = V + ((size_t)bh * SEQ + (size_t)st * 64) * 64;
    const int t = threadIdx.x;
    #pragma unroll
    for (int i = 0; i < 2; ++i) {
        int c  = t + i * 256;
        int s  = c >> 3;
        int d0 = (c & 7) * 8;
        uint4 v = reinterpret_cast<const uint4*>(src)[c];
        u16 e[8];
        e[0] = (u16)(v.x & 0xffff); e[1] = (u16)(v.x >> 16);
        e[2] = (u16)(v.y & 0xffff); e[3] = (u16)(v.y >> 16);
        e[4] = (u16)(v.z & 0xffff); e[5] = (u16)(v.z >> 16);
        e[6] = (u16)(v.w & 0xffff); e[7] = (u16)(v.w >> 16);
        #pragma unroll
        for (int j = 0; j < 8; ++j) T[d0 + j][s] = e[j];
    }
    __syncthreads();
    // permuted gather: dest positions 8g..8g+7 hold kv
    // [2g, 2g+16, 2g+32, 2g+48, 2g+1, 2g+17, 2g+33, 2g+49]
    const int d = t >> 2, seg = t & 3;
    u16* dst = Vt + (size_t)bh * 64 * SEQ + (size_t)d * SEQ + st * 64;
    #pragma unroll
    for (int gg = 0; gg < 2; ++gg) {
        int g = seg * 2 + gg;
        u32 r0 = *reinterpret_cast<const u32*>(&T[d][2 * g]);
        u32 r1 = *reinterpret_cast<const u32*>(&T[d][2 * g + 16]);
        u32 r2 = *reinterpret_cast<const u32*>(&T[d][2 * g + 32]);
        u32 r3 = *reinterpret_cast<const u32*>(&T[d][2 * g + 48]);
        uint4 w;
        w.x = (r0 & 0xffffu) | (r1 << 16);
        w.y = (r2 & 0xffffu) | (r3 << 16);
        w.z = (r0 >> 16) | (r1 & 0xffff0000u);
        w.w = (r2 >> 16) | (r3 & 0xffff0000u);
        *reinterpret_cast<uint4*>(&dst[8 * g]) = w;
    }
}

// ---------------------------------------------------------------------------
// MFMA flash attention (R10 structure restored -- verified 48.0 us):
// 512 threads, 8 waves x 16 q-rows, 4 waves/SIMD. Q pre-scaled -> p =
// exp2(s); truncated-bf16 P; row sums via ones-MFMA on same P fragments.
// P stored k-PERMUTED (p(16t4+l)=4l+t4): one ds_write_b64 per row-quad.
// V k-order pre-permuted identically in v_transpose.
// T15 PV-lag pipeline (KVS triple-buffered) + T5 setprio.
// LDS 66 KB -> 2 blocks/CU. 1D grid (512), XCD swizzle bh = id&31.
// ---------------------------------------------------------------------------
__global__ __launch_bounds__(512, 4) void attn_mfma(
    const u16* __restrict__ Qb_g, const u16* __restrict__ Kb_g,
    const u16* __restrict__ Vt_g, u16* __restrict__ Ch_g)
{
    __shared__ u16 KVS[3][8192];   // per buf: Kb(8KB) | Vt(8KB)
    __shared__ u16 Pb [128 * 72];

    const int tid  = threadIdx.x;
    const int wv   = tid >> 6;          // 0..7
    const int lane = tid & 63;
    const int quad = lane >> 4;
    const int l16  = lane & 15;
    const int id   = blockIdx.x;
    const int bh   = id & 31;           // XCD = id%8 = bh%8
    const int qt   = id >> 5;           // 0..15
    const int qrow = wv * 16;           // wave's 16 q-rows

    const size_t qbase = ((size_t)bh * SEQ + (size_t)qt * 128) * 64;
    const size_t kbh   = (size_t)bh * SEQ * 64;
    const size_t vtbh  = (size_t)bh * 64 * SEQ;

    // ---- Q fragments: direct global -> VGPR (16 q-rows per wave) ----
    bf16x8 qf[2];
    #pragma unroll
    for (int ks = 0; ks < 2; ++ks) {
        size_t o = qbase + (size_t)(qrow + l16) * 64 + ks * 32 + quad * 8;
        qf[ks] = *reinterpret_cast<const bf16x8*>(Qb_g + o);
    }

    // K/V staging: 16 chunks of 1 KB (Kb 0-7, Vt 8-15); 2 per wave
    const u16* sp[2];
    size_t sstep[2];
    int sldb[2];
    #pragma unroll
    for (int j = 0; j < 2; ++j) {
        int c   = wv * 2 + j;            // 0..15
        int arr = c >> 3, cc = c & 7;
        int row = cc * 8 + (lane >> 3);
        int sg  = (lane & 7) ^ (row & 7);
        if (arr == 0) { sp[j] = Kb_g + kbh + (size_t)row * 64 + sg * 8;   sstep[j] = 4096; }
        else          { sp[j] = Vt_g + vtbh + (size_t)row * SEQ + sg * 8; sstep[j] = 64; }
        sldb[j] = arr * 8192 + cc * 1024;
    }

    int fro[4][2];
    #pragma unroll
    for (int t = 0; t < 4; ++t)
        #pragma unroll
        for (int ks = 0; ks < 2; ++ks)
            fro[t][ks] = (t * 16 + l16) * 128 + (((ks * 4 + quad) ^ (l16 & 7)) * 16);

    bf16x8 onesv;
    #pragma unroll
    for (int i = 0; i < 8; ++i) onesv[i] = (__bf16)1.0f;

    f32x4 oacc[4] = {};
    f32x4 lsum = {};

    // ---- pipeline stage helpers ----
    auto S_step = [&](int bufidx, f32x4 (&sacc)[4]) {
        const char* kb = (const char*)KVS[bufidx];
        #pragma unroll
        for (int t4 = 0; t4 < 4; ++t4) {
            bf16x8 kh0 = *reinterpret_cast<const bf16x8*>(kb + fro[t4][0]);
            bf16x8 kh1 = *reinterpret_cast<const bf16x8*>(kb + fro[t4][1]);
            f32x4 a = sacc[t4];
            a = MFMA16(qf[0], kh0, a);
            a = MFMA16(qf[1], kh1, a);
            sacc[t4] = a;
        }
    };

    auto PV_step = [&](int bufidx) {
        const char* vb = (const char*)KVS[bufidx] + 8192;
        bf16x8 bvf[4][2];
        #pragma unroll
        for (int dt = 0; dt < 4; ++dt) {
            bvf[dt][0] = *reinterpret_cast<const bf16x8*>(vb + fro[dt][0]);
            bvf[dt][1] = *reinterpret_cast<const bf16x8*>(vb + fro[dt][1]);
        }
        bf16x8 ap[2];
        #pragma unroll
        for (int ks = 0; ks < 2; ++ks)
            ap[ks] = *reinterpret_cast<const bf16x8*>(
                &Pb[(qrow + l16) * 72 + ks * 32 + quad * 8]);
        #pragma unroll
        for (int dt = 0; dt < 4; ++dt) {
            oacc[dt] = MFMA16(ap[0], bvf[dt][0], oacc[dt]);
            oacc[dt] = MFMA16(ap[1], bvf[dt][1], oacc[dt]);
        }
        lsum = MFMA16(ap[0], onesv, lsum);
        lsum = MFMA16(ap[1], onesv, lsum);
    };

    auto EXP2_step = [&](f32x4 (&sacc)[4]) {
        const int rowb = qrow + quad * 4;
        #pragma unroll
        for (int r = 0; r < 4; ++r) {
            u32 u0 = __float_as_uint(__builtin_amdgcn_exp2f(sacc[0][r]));
            u32 u1 = __float_as_uint(__builtin_amdgcn_exp2f(sacc[1][r]));
            u32 u2 = __float_as_uint(__builtin_amdgcn_exp2f(sacc[2][r]));
            u32 u3 = __float_as_uint(__builtin_amdgcn_exp2f(sacc[3][r]));
            // permuted pack: elements 4*l16 + {0,1,2,3} = t4 0..3 (truncated bf16)
            uint2 w;
            w.x = (u0 >> 16) | (u1 & 0xffff0000u);
            w.y = (u2 >> 16) | (u3 & 0xffff0000u);
            *reinterpret_cast<uint2*>(&Pb[(rowb + r) * 72 + l16 * 4]) = w;
        }
    };

    // ---- prologue: stage tile 0 ----
    #pragma unroll
    for (int j = 0; j < 2; ++j)
        gl16(sp[j], (char*)KVS[0] + sldb[j]);

    // ---- kt = 0 peeled (no PV yet) ----
    {
        __syncthreads();
        #pragma unroll
        for (int j = 0; j < 2; ++j)
            gl16(sp[j] + sstep[j], (char*)KVS[1] + sldb[j]);
        f32x4 sacc[4] = {};
        __builtin_amdgcn_s_setprio(1);
        S_step(0, sacc);
        __builtin_amdgcn_s_setprio(0);
        EXP2_step(sacc);
    }

    // ---- main loop: S(kt) || PV(kt-1), then exp2(kt) ----
    int cur = 1, prv = 0, nxt = 2;
    for (int kt = 1; kt < SEQ / 64; ++kt) {
        __syncthreads();
        if (kt + 1 < SEQ / 64) {
            #pragma unroll
            for (int j = 0; j < 2; ++j)
                gl16(sp[j] + (size_t)(kt + 1) * sstep[j], (char*)KVS[nxt] + sldb[j]);
        }

        f32x4 sacc[4] = {};
        __builtin_amdgcn_s_setprio(1);
        S_step(cur, sacc);
        PV_step(prv);            // reads Pb(kt-1) BEFORE exp2(kt) overwrites it
        __builtin_amdgcn_s_setprio(0);
        EXP2_step(sacc);

        prv = cur; cur = nxt; nxt = (nxt == 2) ? 0 : nxt + 1;
    }

    // ---- drain: PV on the last tile (V landed at last barrier; Pb same-wave)
    __builtin_amdgcn_s_setprio(1);
    PV_step(prv);                // prv == (SEQ/64 - 1) % 3
    __builtin_amdgcn_s_setprio(0);

    // ---- epilogue: normalize by lsum (C-layout rows match oacc), store ----
    u16* Oh = Ch_g + qbase;
    float inv[4];
    #pragma unroll
    for (int r = 0; r < 4; ++r) inv[r] = 1.0f / lsum[r];
    #pragma unroll
    for (int dt = 0; dt < 4; ++dt)
        #pragma unroll
        for (int r = 0; r < 4; ++r) {
            int row = qrow + quad * 4 + r;
            Oh[(size_t)row * 64 + dt * 16 + l16] = f2bf(oacc[dt][r] * inv[r]);
        }
}

// ---------------------------------------------------------------------------
extern "C" void kernel_launch(void* const* d_in, const int* in_sizes, int n_in,
                              void* d_out, int out_size, void* d_ws, size_t ws_size,
                              hipStream_t stream)
{
    const float* x  = (const float*)d_in[0];
    const float* Wq = (const float*)d_in[1];
    const float* bq = (const float*)d_in[2];
    const float* Wk = (const float*)d_in[3];
    const float* bk = (const float*)d_in[4];
    const float* Wv = (const float*)d_in[5];
    const float* bv = (const float*)d_in[6];
    const float* Wo = (const float*)d_in[7];
    const float* bo = (const float*)d_in[8];
    float* out = (float*)d_out;

    const int M = BATCH * SEQ;        // 4096
    const int N = D_MODEL;            // 1024
    const size_t NE = (size_t)M * N;  // 4,194,304
    const size_t NW = (size_t)N * N;  // 1,048,576

    u16* w16 = (u16*)d_ws;
    u16* Xh   = w16;
    u16* Qb   = Xh   + NE;
    u16* Kb   = Qb   + NE;
    u16* Vb   = Kb   + NE;
    u16* Vtb  = Vb   + NE;
    u16* Ctxh = Vtb  + NE;
    u16* WTqh = Ctxh + NE;
    u16* WTql = WTqh + NW;
    u16* WTkh = WTql + NW;
    u16* WTkl = WTkh + NW;
    u16* WTvh = WTkl + NW;
    u16* WTvl = WTvh + NW;
    u16* WToh = WTvl + NW;
    u16* WTol = WToh + NW;

    // conversions (single launch; lo computed only for Wo)
    conv_all<<<dim3(4096 + 1024), dim3(256), 0, stream>>>(
        x, Xh, (int)(NE / 4),
        Wq, Wk, Wv, Wo, WTqh, WTql, WTkh, WTkl, WTvh, WTvl, WToh, WTol);

    // fused QKV projection (SINGLE-term, single-phase 2-deep counted-vmcnt)
    gemm_qkv<<<dim3(N / 64, M / 128), dim3(256), 0, stream>>>(
        Xh, WTqh, WTkh, WTvh, bq, bk, bv, Qb, Kb, Vb);

    // transpose V per contiguous reshape slab (k permuted to match packed P)
    v_transpose<<<dim3(SEQ / 64, BH), dim3(256), 0, stream>>>(Vb, Vtb);

    // attention (R10 structure: 512 threads, 8 waves x 16 q-rows)
    attn_mfma<<<dim3((SEQ / 128) * BH), dim3(512), 0, stream>>>(Qb, Kb, Vtb, Ctxh);

    // output projection (2-term, 128x64 tile, 2-phase counted-vmcnt)
    gemm_oproj<<<dim3(N / 64, M / 128), dim3(256), 0, stream>>>(
        Ctxh, WToh, WTol, bo, out);
}